// Round 5
// baseline (186.323 us; speedup 1.0000x reference)
//
#include <hip/hip_runtime.h>

// GripperRegionNetwork: B=512, G=8192, C=6, REGION_NUM=1024
//
// Three kernels:
//  1) xform_kernel (B threads): per-batch 3x3 row transform + center (f64 trig
//     isolated). Writes 12 floats/batch to d_ws.
//  2) mask_kernel (B*G/256 blocks x 256): transform + box test per point, wave
//     ballot -> per-64-pt-chunk uint64 mask + popcount into d_ws. Fully
//     parallel, no barriers, streams the 100 MB input once.
//  3) emit_kernel (B*4 blocks x 256): per batch, load chunk masks+counts,
//     wave-parallel prefix scan, expand set bits into s_idx (ordered
//     compaction), then gather + write this block's RN/4 output slice.
//
// Outputs concatenated in d_out (all f32; int values exact in f32):
//  0: gripper_pc (B,RN,6)  1: gripper_pc_index (B,RN)
//  2: gripper_pc_index_inall (B,RN)  3: true_mask (B)

__device__ __forceinline__ float fm(float a, float b) { return __fmul_rn(a, b); }
__device__ __forceinline__ float fa(float a, float b) { return __fadd_rn(a, b); }
__device__ __forceinline__ float fs(float a, float b) { return __fsub_rn(a, b); }
__device__ __forceinline__ float fd(float a, float b) { return __fdiv_rn(a, b); }

// xf layout per batch: [r0x r0y r0z r1x][r1y r1z r2x r2y][r2z cx cy cz]
extern "C" __global__ void xform_kernel(const float* __restrict__ grasp,
                                        float* __restrict__ xf, int B) {
    int b = blockIdx.x * blockDim.x + threadIdx.x;
    if (b >= B) return;
    const float* gr = grasp + (size_t)b * 7;

    float cx = gr[0], cy = gr[1], cz = gr[2];
    float vx = gr[3], vy = gr[4], vz = gr[5];
    float angle = gr[6];
    float c = (float)cos((double)angle);
    float s = (float)sin((double)angle);

    // axis_y = normalize_fix(v, [0,1,0]); eps=1e-12
    float n  = __fsqrt_rn(fa(fa(fm(vx, vx), fm(vy, vy)), fm(vz, vz)));
    float dn = fa(n, 1e-12f);
    float ayx = fd(vx, dn), ayy = fd(vy, dn), ayz = fd(vz, dn);
    if (n == 0.0f) { ayx = 0.0f; ayy = 1.0f; ayz = 0.0f; }

    // axis_x = normalize_fix([ay.y, -ay.x, 0], [1,0,0])
    float bx = ayy, by = -ayx;
    float n2  = __fsqrt_rn(fa(fa(fm(bx, bx), fm(by, by)), 0.0f));
    float dn2 = fa(n2, 1e-12f);
    float axx = fd(bx, dn2), axy = fd(by, dn2), axz = fd(0.0f, dn2);
    if (n2 == 0.0f) { axx = 1.0f; axy = 0.0f; axz = 0.0f; }

    // axis_z = cross(axis_x, axis_y); /where(nz==0,1,nz); fallback [0,0,1]
    float zx = fs(fm(axy, ayz), fm(axz, ayy));
    float zy = fs(fm(axz, ayx), fm(axx, ayz));
    float zz = fs(fm(axx, ayy), fm(axy, ayx));
    float nz = __fsqrt_rn(fa(fa(fm(zx, zx), fm(zy, zy)), fm(zz, zz)));
    float dz = (nz == 0.0f) ? 1.0f : nz;
    zx = fd(zx, dz); zy = fd(zy, dz); zz = fd(zz, dz);
    if (nz == 0.0f) { zx = 0.0f; zy = 0.0f; zz = 1.0f; }

    // approach = normalize_fix(M[:,:,0],[1,0,0]); M[:,0] = axis_x*c + axis_z*s
    float px = fa(fm(axx, c), fm(zx, s));
    float py = fa(fm(axy, c), fm(zy, s));
    float pz = fa(fm(axz, c), fm(zz, s));
    float n3  = __fsqrt_rn(fa(fa(fm(px, px), fm(py, py)), fm(pz, pz)));
    float dn3 = fa(n3, 1e-12f);
    float apx = fd(px, dn3), apy = fd(py, dn3), apz = fd(pz, dn3);
    if (n3 == 0.0f) { apx = 1.0f; apy = 0.0f; apz = 0.0f; }

    // minor = cross(approach, axis_y)
    float mx = fs(fm(apy, ayz), fm(apz, ayy));
    float my = fs(fm(apz, ayx), fm(apx, ayz));
    float mz = fs(fm(apx, ayy), fm(apy, ayx));

    float* o = xf + (size_t)b * 12;
    o[0] = apx; o[1] = apy; o[2]  = apz;
    o[3] = ayx; o[4] = ayy; o[5]  = ayz;
    o[6] = mx;  o[7] = my;  o[8]  = mz;
    o[9] = cx;  o[10] = cy; o[11] = cz;
}

#define MT 256
#define ESPLIT 4

extern "C" __global__ void __launch_bounds__(MT)
mask_kernel(const float* __restrict__ gp,    // (B,G,6)
            const float* __restrict__ xf,    // (B,12)
            const float* __restrict__ widths_p,
            const float* __restrict__ height_p,
            const float* __restrict__ depths_p,
            unsigned long long* __restrict__ masks,  // (B, G/64)
            int* __restrict__ counts,                // (B, G/64)
            int G) {
    const int spb  = G >> 8;                 // 256-point segments per batch
    const int b    = blockIdx.x / spb;
    const int seg  = blockIdx.x - b * spb;
    const int tid  = threadIdx.x;
    const int lane = tid & 63;

    const float4 q0 = *(const float4*)(xf + (size_t)b * 12 + 0);
    const float4 q1 = *(const float4*)(xf + (size_t)b * 12 + 4);
    const float4 q2 = *(const float4*)(xf + (size_t)b * 12 + 8);
    const float r0x = q0.x, r0y = q0.y, r0z = q0.z;
    const float r1x = q0.w, r1y = q1.x, r1z = q1.y;
    const float r2x = q1.z, r2y = q1.w, r2z = q2.x;
    const float cx  = q2.y, cy  = q2.z, cz  = q2.w;

    const float x_lim = fm(*depths_p, 0.5f);
    const float y_lim = fm(*widths_p, 0.5f);
    const float z_lim = fm(*height_p, 0.5f);

    const int g = (seg << 8) + tid;
    const float* p = gp + ((size_t)b * G + (size_t)g) * 6;
    const float2 l0 = *(const float2*)(p);      // x,y
    const float2 l1 = *(const float2*)(p + 2);  // z,f3
    const float dx = fs(l0.x, cx), dy = fs(l0.y, cy), dz = fs(l1.x, cz);
    const float x = fa(fa(fm(r0x, dx), fm(r0y, dy)), fm(r0z, dz));
    const float y = fa(fa(fm(r1x, dx), fm(r1y, dy)), fm(r1z, dz));
    const float z = fa(fa(fm(r2x, dx), fm(r2y, dy)), fm(r2z, dz));
    const bool m = (x > 0.0f) & (x < x_lim) & (y > -y_lim) & (y < y_lim) &
                   (z > -z_lim) & (z < z_lim);

    const unsigned long long bal = __ballot(m);
    if (lane == 0) {
        const size_t o = (size_t)b * (G >> 6) + (g >> 6);
        masks[o]  = bal;
        counts[o] = __popcll(bal);
    }
}

extern "C" __global__ void __launch_bounds__(MT)
emit_kernel(const float* __restrict__ gp,    // (B,G,6)
            const int*   __restrict__ gidx,  // (B,G)
            const unsigned long long* __restrict__ masks,
            const int*   __restrict__ counts,
            const float* __restrict__ xf,
            float* __restrict__ out,
            int B, int G, int RN) {
    const int b     = blockIdx.x / ESPLIT;
    const int split = blockIdx.x - b * ESPLIT;
    const int tid   = threadIdx.x;
    const int lane  = tid & 63;
    const int wv    = tid >> 6;
    const int NCH   = G >> 6;                // chunks per batch (<=256)

    __shared__ unsigned long long s_mask[256];
    __shared__ int s_pref[256];
    __shared__ int s_total;
    extern __shared__ int s_idx[];           // RN entries

    for (int c = tid; c < NCH; c += MT)
        s_mask[c] = masks[(size_t)b * NCH + c];

    if (wv == 0) {
        int carry = 0;
        for (int cb = 0; cb < NCH; cb += 64) {
            const int c = counts[(size_t)b * NCH + cb + lane];
            int x = c;
            #pragma unroll
            for (int d2 = 1; d2 < 64; d2 <<= 1) {
                int v = __shfl_up(x, d2, 64);
                if (lane >= d2) x += v;
            }
            s_pref[cb + lane] = carry + (x - c);   // exclusive prefix
            carry += __shfl(x, 63, 64);
        }
        if (lane == 0) s_total = carry;
    }
    __syncthreads();

    // expand set bits -> ordered s_idx[0..min(count,RN))
    for (int c = wv; c < NCH; c += (MT / 64)) {
        const unsigned long long mk = s_mask[c];
        const int base = s_pref[c];
        if (mk != 0ull && base < RN) {
            const int pos = base + __popcll(mk & ((1ull << lane) - 1ull));
            if (((mk >> lane) & 1ull) && pos < RN) s_idx[pos] = (c << 6) + lane;
        }
    }
    __syncthreads();

    const int count = s_total;

    const float4 q0 = *(const float4*)(xf + (size_t)b * 12 + 0);
    const float4 q1 = *(const float4*)(xf + (size_t)b * 12 + 4);
    const float4 q2 = *(const float4*)(xf + (size_t)b * 12 + 8);
    const float r0x = q0.x, r0y = q0.y, r0z = q0.z;
    const float r1x = q0.w, r1y = q1.x, r1z = q1.y;
    const float r2x = q1.z, r2y = q1.w, r2z = q2.x;
    const float cx  = q2.y, cy  = q2.z, cz  = q2.w;

    float* __restrict__ out0 = out;                        // (B,RN,6)
    float* __restrict__ out1 = out + (size_t)B * RN * 6;   // (B,RN)
    float* __restrict__ out2 = out1 + (size_t)B * RN;      // (B,RN)
    float* __restrict__ out3 = out2 + (size_t)B * RN;      // (B)

    const float* __restrict__ gpb = gp + (size_t)b * G * 6;
    const int chunk = (RN + ESPLIT - 1) / ESPLIT;
    const int j0 = split * chunk;
    const int j1 = (j0 + chunk < RN) ? (j0 + chunk) : RN;

    if (count > 5) {
        const int m = count < RN ? count : RN;  // j%count == j%m for j<RN
        for (int j = j0 + tid; j < j1; j += MT) {
            const int i = s_idx[j % m];
            const float* p = gpb + (size_t)i * 6;
            const float2 l0 = *(const float2*)(p);      // x,y
            const float2 l1 = *(const float2*)(p + 2);  // z,f3
            const float2 l2 = *(const float2*)(p + 4);  // f4,f5
            const float dx = fs(l0.x, cx), dy = fs(l0.y, cy), dz = fs(l1.x, cz);
            const float x = fa(fa(fm(r0x, dx), fm(r0y, dy)), fm(r0z, dz));
            const float y = fa(fa(fm(r1x, dx), fm(r1y, dy)), fm(r1z, dz));
            const float z = fa(fa(fm(r2x, dx), fm(r2y, dy)), fm(r2z, dz));
            float* o = out0 + ((size_t)b * RN + j) * 6;
            *(float2*)(o + 0) = make_float2(x, y);
            *(float2*)(o + 2) = make_float2(z, l1.y);
            *(float2*)(o + 4) = l2;
            out1[(size_t)b * RN + j] = (float)i;
            out2[(size_t)b * RN + j] = (float)gidx[(size_t)b * G + i];
        }
        if (split == 0 && tid == 0) out3[b] = 1.0f;
    } else {
        for (int j = j0 + tid; j < j1; j += MT) {
            float* o = out0 + ((size_t)b * RN + j) * 6;
            const float2 neg = make_float2(-1.0f, -1.0f);
            *(float2*)(o + 0) = neg;
            *(float2*)(o + 2) = neg;
            *(float2*)(o + 4) = neg;
            out1[(size_t)b * RN + j] = -1.0f;
            out2[(size_t)b * RN + j] = -1.0f;
        }
        if (split == 0 && tid == 0) out3[b] = 0.0f;
    }
}

extern "C" void kernel_launch(void* const* d_in, const int* in_sizes, int n_in,
                              void* d_out, int out_size, void* d_ws, size_t ws_size,
                              hipStream_t stream) {
    const float* gp     = (const float*)d_in[0];
    const int*   gidx   = (const int*)d_in[1];
    const float* grasp  = (const float*)d_in[2];
    const float* widths = (const float*)d_in[3];
    const float* height = (const float*)d_in[4];
    const float* depths = (const float*)d_in[5];
    float* out = (float*)d_out;

    const int B  = in_sizes[2] / 7;
    const int G  = in_sizes[1] / B;
    const int RN = (out_size / B - 1) / 8;   // out_size = B*(8*RN+1)
    const int NCH = G >> 6;

    // d_ws layout: xf (B*12 f32) | masks (B*NCH u64) | counts (B*NCH i32)
    float* xf = (float*)d_ws;
    size_t off = ((size_t)B * 12 * sizeof(float) + 255) & ~(size_t)255;
    unsigned long long* masks = (unsigned long long*)((char*)d_ws + off);
    off += (size_t)B * NCH * sizeof(unsigned long long);
    int* cnts = (int*)((char*)d_ws + off);

    xform_kernel<<<(B + 255) / 256, 256, 0, stream>>>(grasp, xf, B);

    mask_kernel<<<B * (G >> 8), MT, 0, stream>>>(gp, xf, widths, height,
                                                 depths, masks, cnts, G);

    const size_t smem = (size_t)RN * sizeof(int);
    emit_kernel<<<B * ESPLIT, MT, smem, stream>>>(gp, gidx, masks, cnts, xf,
                                                  out, B, G, RN);
}

// Round 6
// 179.194 us; speedup vs baseline: 1.0398x; 1.0398x over previous
//
#include <hip/hip_runtime.h>

// GripperRegionNetwork: B=512, G=8192, C=6, REGION_NUM=1024
//
// Two kernels (fused structure — best measured at 180.4 µs bench):
//  1) xform_kernel (B threads): per-batch 3x3 row transform + center (f64 trig
//     isolated here to keep hot-kernel VGPRs low). Writes 12 f32/batch to d_ws.
//  2) gripper_kernel: one 1024-thread block per batch.
//     Phase B: 2 points/thread via 3x float4 (48B/thread fully coalesced),
//       dual ballot -> ordered compaction into s_idx, 1 barrier/iter, 4 iters.
//     Phase C: cyclic gather (L2-hot lines) + output emit.
//
// Outputs concatenated in d_out (all f32; int values exact in f32):
//  0: gripper_pc (B,RN,6)  1: gripper_pc_index (B,RN)
//  2: gripper_pc_index_inall (B,RN)  3: true_mask (B)

__device__ __forceinline__ float fm(float a, float b) { return __fmul_rn(a, b); }
__device__ __forceinline__ float fa(float a, float b) { return __fadd_rn(a, b); }
__device__ __forceinline__ float fs(float a, float b) { return __fsub_rn(a, b); }
__device__ __forceinline__ float fd(float a, float b) { return __fdiv_rn(a, b); }

// xf layout per batch: [r0x r0y r0z r1x][r1y r1z r2x r2y][r2z cx cy cz]
extern "C" __global__ void xform_kernel(const float* __restrict__ grasp,
                                        float* __restrict__ xf, int B) {
    int b = blockIdx.x * blockDim.x + threadIdx.x;
    if (b >= B) return;
    const float* gr = grasp + (size_t)b * 7;

    float cx = gr[0], cy = gr[1], cz = gr[2];
    float vx = gr[3], vy = gr[4], vz = gr[5];
    float angle = gr[6];
    float c = (float)cos((double)angle);
    float s = (float)sin((double)angle);

    // axis_y = normalize_fix(v, [0,1,0]); eps=1e-12
    float n  = __fsqrt_rn(fa(fa(fm(vx, vx), fm(vy, vy)), fm(vz, vz)));
    float dn = fa(n, 1e-12f);
    float ayx = fd(vx, dn), ayy = fd(vy, dn), ayz = fd(vz, dn);
    if (n == 0.0f) { ayx = 0.0f; ayy = 1.0f; ayz = 0.0f; }

    // axis_x = normalize_fix([ay.y, -ay.x, 0], [1,0,0])
    float bx = ayy, by = -ayx;
    float n2  = __fsqrt_rn(fa(fa(fm(bx, bx), fm(by, by)), 0.0f));
    float dn2 = fa(n2, 1e-12f);
    float axx = fd(bx, dn2), axy = fd(by, dn2), axz = fd(0.0f, dn2);
    if (n2 == 0.0f) { axx = 1.0f; axy = 0.0f; axz = 0.0f; }

    // axis_z = cross(axis_x, axis_y); /where(nz==0,1,nz); fallback [0,0,1]
    float zx = fs(fm(axy, ayz), fm(axz, ayy));
    float zy = fs(fm(axz, ayx), fm(axx, ayz));
    float zz = fs(fm(axx, ayy), fm(axy, ayx));
    float nz = __fsqrt_rn(fa(fa(fm(zx, zx), fm(zy, zy)), fm(zz, zz)));
    float dz = (nz == 0.0f) ? 1.0f : nz;
    zx = fd(zx, dz); zy = fd(zy, dz); zz = fd(zz, dz);
    if (nz == 0.0f) { zx = 0.0f; zy = 0.0f; zz = 1.0f; }

    // approach = normalize_fix(M[:,:,0],[1,0,0]); M[:,0] = axis_x*c + axis_z*s
    float px = fa(fm(axx, c), fm(zx, s));
    float py = fa(fm(axy, c), fm(zy, s));
    float pz = fa(fm(axz, c), fm(zz, s));
    float n3  = __fsqrt_rn(fa(fa(fm(px, px), fm(py, py)), fm(pz, pz)));
    float dn3 = fa(n3, 1e-12f);
    float apx = fd(px, dn3), apy = fd(py, dn3), apz = fd(pz, dn3);
    if (n3 == 0.0f) { apx = 1.0f; apy = 0.0f; apz = 0.0f; }

    // minor = cross(approach, axis_y)
    float mx = fs(fm(apy, ayz), fm(apz, ayy));
    float my = fs(fm(apz, ayx), fm(apx, ayz));
    float mz = fs(fm(apx, ayy), fm(apy, ayx));

    float* o = xf + (size_t)b * 12;
    o[0] = apx; o[1] = apy; o[2]  = apz;
    o[3] = ayx; o[4] = ayy; o[5]  = ayz;
    o[6] = mx;  o[7] = my;  o[8]  = mz;
    o[9] = cx;  o[10] = cy; o[11] = cz;
}

#define NTHREADS 1024
#define NWAVES (NTHREADS / 64)

extern "C" __global__ void __launch_bounds__(NTHREADS)
gripper_kernel(const float* __restrict__ gp,    // (B,G,6)
               const int*   __restrict__ gidx,  // (B,G)
               const float* __restrict__ xf,    // (B,12)
               const float* __restrict__ widths_p,
               const float* __restrict__ height_p,
               const float* __restrict__ depths_p,
               float* __restrict__ out,
               int B, int G, int RN) {
    const int b    = blockIdx.x;
    const int tid  = threadIdx.x;
    const int lane = tid & 63;
    const int wave = tid >> 6;

    extern __shared__ int s_idx[];          // RN entries
    __shared__ int s_cnt[2][NWAVES];

    const float4 q0c = *(const float4*)(xf + (size_t)b * 12 + 0);
    const float4 q1c = *(const float4*)(xf + (size_t)b * 12 + 4);
    const float4 q2c = *(const float4*)(xf + (size_t)b * 12 + 8);
    const float r0x = q0c.x, r0y = q0c.y, r0z = q0c.z;
    const float r1x = q0c.w, r1y = q1c.x, r1z = q1c.y;
    const float r2x = q1c.z, r2y = q1c.w, r2z = q2c.x;
    const float cx  = q2c.y, cy  = q2c.z, cz  = q2c.w;

    const float x_lim = fm(*depths_p, 0.5f);
    const float y_lim = fm(*widths_p, 0.5f);
    const float z_lim = fm(*height_p, 0.5f);

    const float* __restrict__ gpb = gp + (size_t)b * G * 6;

    // ---- Phase B: ordered compaction, 2 points/thread, 3x float4 loads ----
    int running = 0;
    const int niter = G / (2 * NTHREADS);   // 4
    for (int it = 0; it < niter; ++it) {
        const int base = it * 2 * NTHREADS;
        const float4* q = (const float4*)(gpb + (size_t)base * 6) + 3 * tid;
        const float4 a0 = q[0];   // p0: x y z f3
        const float4 a1 = q[1];   // p0: f4 f5 | p1: x y
        const float4 a2 = q[2];   // p1: z f3 f4 f5

        // p0 = base + 2*tid, p1 = p0 + 1
        float dx = fs(a0.x, cx), dy = fs(a0.y, cy), dz = fs(a0.z, cz);
        const float x0 = fa(fa(fm(r0x, dx), fm(r0y, dy)), fm(r0z, dz));
        const float y0 = fa(fa(fm(r1x, dx), fm(r1y, dy)), fm(r1z, dz));
        const float z0 = fa(fa(fm(r2x, dx), fm(r2y, dy)), fm(r2z, dz));
        const bool m0 = (x0 > 0.0f) & (x0 < x_lim) & (y0 > -y_lim) &
                        (y0 < y_lim) & (z0 > -z_lim) & (z0 < z_lim);

        dx = fs(a1.z, cx); dy = fs(a1.w, cy); dz = fs(a2.x, cz);
        const float x1 = fa(fa(fm(r0x, dx), fm(r0y, dy)), fm(r0z, dz));
        const float y1 = fa(fa(fm(r1x, dx), fm(r1y, dy)), fm(r1z, dz));
        const float z1 = fa(fa(fm(r2x, dx), fm(r2y, dy)), fm(r2z, dz));
        const bool m1 = (x1 > 0.0f) & (x1 < x_lim) & (y1 > -y_lim) &
                        (y1 < y_lim) & (z1 > -z_lim) & (z1 < z_lim);

        const unsigned long long bal0 = __ballot(m0);
        const unsigned long long bal1 = __ballot(m1);
        if (lane == 0)
            s_cnt[it & 1][wave] = __popcll(bal0) + __popcll(bal1);
        __syncthreads();

        int off = running, tot = 0;
        #pragma unroll
        for (int w = 0; w < NWAVES; ++w) {
            const int cw = s_cnt[it & 1][w];
            if (w < wave) off += cw;
            tot += cw;
        }
        const unsigned long long below = (1ull << lane) - 1ull;
        const int pos0 = off + __popcll(bal0 & below) + __popcll(bal1 & below);
        const int pos1 = pos0 + (int)((bal0 >> lane) & 1ull);
        const int p0 = base + 2 * tid;
        if (m0 && pos0 < RN) s_idx[pos0] = p0;
        if (m1 && pos1 < RN) s_idx[pos1] = p0 + 1;
        running += tot;
    }
    __syncthreads();

    const int count = running;

    // ---- Phase C: emit outputs (gather lines are L2-hot) ----
    float* __restrict__ out0 = out;                        // (B,RN,6)
    float* __restrict__ out1 = out + (size_t)B * RN * 6;   // (B,RN)
    float* __restrict__ out2 = out1 + (size_t)B * RN;      // (B,RN)
    float* __restrict__ out3 = out2 + (size_t)B * RN;      // (B)

    if (count > 5) {
        const int m = count < RN ? count : RN;  // j%count == j%m for j<RN
        for (int j = tid; j < RN; j += NTHREADS) {
            const int i = s_idx[j % m];
            const float* p = gpb + (size_t)i * 6;
            const float2 l0 = *(const float2*)(p);      // x,y
            const float2 l1 = *(const float2*)(p + 2);  // z,f3
            const float2 l2 = *(const float2*)(p + 4);  // f4,f5
            const float dx = fs(l0.x, cx), dy = fs(l0.y, cy), dz = fs(l1.x, cz);
            const float x = fa(fa(fm(r0x, dx), fm(r0y, dy)), fm(r0z, dz));
            const float y = fa(fa(fm(r1x, dx), fm(r1y, dy)), fm(r1z, dz));
            const float z = fa(fa(fm(r2x, dx), fm(r2y, dy)), fm(r2z, dz));
            float* o = out0 + ((size_t)b * RN + j) * 6;
            *(float2*)(o + 0) = make_float2(x, y);
            *(float2*)(o + 2) = make_float2(z, l1.y);
            *(float2*)(o + 4) = l2;
            out1[(size_t)b * RN + j] = (float)i;
            out2[(size_t)b * RN + j] = (float)gidx[(size_t)b * G + i];
        }
        if (tid == 0) out3[b] = 1.0f;
    } else {
        for (int j = tid; j < RN; j += NTHREADS) {
            float* o = out0 + ((size_t)b * RN + j) * 6;
            const float2 neg = make_float2(-1.0f, -1.0f);
            *(float2*)(o + 0) = neg;
            *(float2*)(o + 2) = neg;
            *(float2*)(o + 4) = neg;
            out1[(size_t)b * RN + j] = -1.0f;
            out2[(size_t)b * RN + j] = -1.0f;
        }
        if (tid == 0) out3[b] = 0.0f;
    }
}

extern "C" void kernel_launch(void* const* d_in, const int* in_sizes, int n_in,
                              void* d_out, int out_size, void* d_ws, size_t ws_size,
                              hipStream_t stream) {
    const float* gp     = (const float*)d_in[0];
    const int*   gidx   = (const int*)d_in[1];
    const float* grasp  = (const float*)d_in[2];
    const float* widths = (const float*)d_in[3];
    const float* height = (const float*)d_in[4];
    const float* depths = (const float*)d_in[5];
    float* out = (float*)d_out;
    float* xf  = (float*)d_ws;   // B*12 floats

    const int B  = in_sizes[2] / 7;
    const int G  = in_sizes[1] / B;
    const int RN = (out_size / B - 1) / 8;   // out_size = B*(8*RN+1)

    xform_kernel<<<(B + 255) / 256, 256, 0, stream>>>(grasp, xf, B);

    const size_t smem = (size_t)RN * sizeof(int);
    gripper_kernel<<<B, NTHREADS, smem, stream>>>(gp, gidx, xf, widths,
                                                  height, depths, out, B, G, RN);
}